// Round 3
// baseline (567.287 us; speedup 1.0000x reference)
//
#include <hip/hip_runtime.h>
#include <hip/hip_bf16.h>

#define EMB 768
#define HD 1024
#define D3 128
#define CTXN 512
#define BB 8
#define SS 64

typedef __attribute__((ext_vector_type(8))) short short8v;
typedef __attribute__((ext_vector_type(4))) float f32x4;

__device__ __forceinline__ float fast_tanh(float x) {
  float e = __expf(2.f * x);
  return 1.f - 2.f * __builtin_amdgcn_rcpf(e + 1.f);
}
__device__ __forceinline__ float bf2f(__hip_bfloat16 x) { return __bfloat162float(x); }

// ---------------- kcast: Maug1=[W_s;b_s] bf16, W1T = W_s^T bf16, Gmat = h0 bf16, qb
__global__ __launch_bounds__(256) void kcast(const float* __restrict__ W_s,
                                             const float* __restrict__ b_s,
                                             const float* __restrict__ context,
                                             const float* __restrict__ b_in,
                                             const float* __restrict__ W_att_in,
                                             const float* __restrict__ b_att_in,
                                             __hip_bfloat16* __restrict__ Maug1,
                                             __hip_bfloat16* __restrict__ W1T,
                                             __hip_bfloat16* __restrict__ Gmat,
                                             float* __restrict__ qb) {
  int blk = blockIdx.x, tid = threadIdx.x;
  __shared__ float red[2][128];
  if (blk == 256) {  // qb[d] = b_in @ W_att_in[:1024,d] + b_att_in[d]
    int d = tid & 127, h = tid >> 7;
    float acc = 0.f;
    for (int k = h * 512; k < h * 512 + 512; ++k) acc += b_in[k] * W_att_in[k * D3 + d];
    red[h][d] = acc;
    __syncthreads();
    if (h == 0) qb[d] = red[0][d] + red[1][d] + b_att_in[d];
    return;
  }
  int r0 = (blk >> 4) * 64, c0 = (blk & 15) * 64;
  __shared__ __hip_bfloat16 t[64][65];
  for (int i = tid; i < 64 * 64; i += 256) {
    int r = i >> 6, c = i & 63;
    __hip_bfloat16 bv = __float2bfloat16(W_s[(long)(r0 + r) * HD + c0 + c]);
    Maug1[(long)(r0 + r) * HD + c0 + c] = bv;
    t[r][c] = bv;
  }
  __syncthreads();
  for (int i = tid; i < 64 * 64; i += 256) {
    int c = i >> 6, r = i & 63;
    W1T[(long)(c0 + c) * HD + r0 + r] = t[r][c];
  }
  if (blk == 0) {
    for (int i = tid; i < HD; i += 256)
      Maug1[(long)HD * HD + i] = __float2bfloat16(b_s[i]);
    for (int i = tid; i < BB * HD; i += 256) {
      int b = i >> 10, k = i & 1023;
      Gmat[i] = __float2bfloat16(context[((long)b * CTXN + (CTXN - 1)) * HD + k]);
    }
  }
}

// ---------------- gemmbt: BM=128 x BN=64 tile MFMA GEMM.
// C[M,N] = A[M,K]@B[K,N] (+bias_f row-bcast)(+addrow added to row M-1)
// outputs: Cf fp32, Cb bf16, CbT bf16 transposed (stride HD, rows<HD only)
template <bool AF32, bool BF32>
__global__ __launch_bounds__(256) void gemmbt(const void* __restrict__ Ap, int lda, int M,
                                              const void* __restrict__ Bp, int ldb, int N,
                                              int K,
                                              const __hip_bfloat16* __restrict__ addrow,
                                              const float* __restrict__ bias_f,
                                              float* __restrict__ Cf,
                                              __hip_bfloat16* __restrict__ Cb,
                                              __hip_bfloat16* __restrict__ CbT) {
  const float* Af = (const float*)Ap;
  const __hip_bfloat16* Ab = (const __hip_bfloat16*)Ap;
  const float* Bf = (const float*)Bp;
  const __hip_bfloat16* Bb = (const __hip_bfloat16*)Bp;
  __shared__ __hip_bfloat16 As[128][40];  // 80B row stride: <=2-way conflicts (free)
  __shared__ __hip_bfloat16 Bt[64][40];   // B tile transposed [n][k]
  int tid = threadIdx.x;
  int lane = tid & 63, wid = tid >> 6;
  int l16 = lane & 15, g = lane >> 4;
  int bm0 = blockIdx.x * 128, bn0 = blockIdx.y * 64;
  int wm = wid * 32;  // wave's 32 rows
  f32x4 acc[2][4] = {};
  int arow = tid >> 1, aseg = tid & 1;  // A: 128 rows x 32k, 16 elems/thread
  int brow = tid >> 3, bseg = tid & 7;  // B: 32 rows x 64n, 8 elems/thread
  for (int k0 = 0; k0 < K; k0 += 32) {
    __syncthreads();
    {  // stage A
      int gr = bm0 + arow;
      __hip_bfloat16 tmp[16];
      if (gr < M) {
        if (AF32) {
          const float* src = &Af[(long)gr * lda + k0 + aseg * 16];
#pragma unroll
          for (int j = 0; j < 16; ++j) tmp[j] = __float2bfloat16(src[j]);
        } else {
          const __hip_bfloat16* src = &Ab[(long)gr * lda + k0 + aseg * 16];
          *(short8v*)tmp = *(const short8v*)src;
          *(short8v*)(tmp + 8) = *(const short8v*)(src + 8);
        }
      } else {
#pragma unroll
        for (int j = 0; j < 16; ++j) tmp[j] = __float2bfloat16(0.f);
      }
      *(short8v*)&As[arow][aseg * 16] = *(short8v*)tmp;
      *(short8v*)&As[arow][aseg * 16 + 8] = *(short8v*)(tmp + 8);
    }
    {  // stage B transposed
      int gk = k0 + brow;
      __hip_bfloat16 tv[8];
      if (BF32) {
        const float* src = &Bf[(long)gk * ldb + bn0 + bseg * 8];
#pragma unroll
        for (int j = 0; j < 8; ++j) tv[j] = __float2bfloat16(src[j]);
      } else {
        *(short8v*)tv = *(const short8v*)&Bb[(long)gk * ldb + bn0 + bseg * 8];
      }
#pragma unroll
      for (int j = 0; j < 8; ++j) Bt[bseg * 8 + j][brow] = tv[j];
    }
    __syncthreads();
    short8v a0 = *(const short8v*)&As[wm + l16][g * 8];
    short8v a1 = *(const short8v*)&As[wm + 16 + l16][g * 8];
    short8v bfr[4];
#pragma unroll
    for (int j = 0; j < 4; ++j) bfr[j] = *(const short8v*)&Bt[j * 16 + l16][g * 8];
#pragma unroll
    for (int j = 0; j < 4; ++j) {
      acc[0][j] = __builtin_amdgcn_mfma_f32_16x16x32_bf16(a0, bfr[j], acc[0][j], 0, 0, 0);
      acc[1][j] = __builtin_amdgcn_mfma_f32_16x16x32_bf16(a1, bfr[j], acc[1][j], 0, 0, 0);
    }
  }
#pragma unroll
  for (int i = 0; i < 2; ++i)
#pragma unroll
    for (int j = 0; j < 4; ++j)
#pragma unroll
      for (int r = 0; r < 4; ++r) {
        int grow = bm0 + wm + i * 16 + g * 4 + r;
        int gcol = bn0 + j * 16 + l16;
        if (grow < M && gcol < N) {
          float v = acc[i][j][r];
          if (bias_f) v += bias_f[gcol];
          if (addrow && grow == M - 1) v += bf2f(addrow[gcol]);
          if (Cf) Cf[(long)grow * N + gcol] = v;
          if (Cb) Cb[(long)grow * N + gcol] = __float2bfloat16(v);
          if (CbT && grow < HD) CbT[(long)gcol * HD + grow] = __float2bfloat16(v);
        }
      }
}

// ---------------- smgemm: small-M GEMM, no LDS, B pre-transposed BT[N=1024][K=1024]
template <int MT>
__global__ __launch_bounds__(256) void smgemm(const __hip_bfloat16* __restrict__ A, int M,
                                              const __hip_bfloat16* __restrict__ BT,
                                              const float* __restrict__ bias_f,
                                              const __hip_bfloat16* __restrict__ bias_bf,
                                              float* __restrict__ Cf, int cf_scatter,
                                              __hip_bfloat16* __restrict__ Cb) {
  int lane = threadIdx.x & 63, w = threadIdx.x >> 6;
  int n0 = blockIdx.x * 64 + w * 16;
  int l16 = lane & 15, g = lane >> 4;
  f32x4 acc[MT] = {};
  const long bbase = (long)(n0 + l16) * HD;
#pragma unroll 4
  for (int k0 = 0; k0 < HD; k0 += 32) {
    short8v bfr = *(const short8v*)&BT[bbase + k0 + g * 8];
#pragma unroll
    for (int i = 0; i < MT; ++i) {
      int row = i * 16 + l16;
      short8v afr = {};
      if (row < M) afr = *(const short8v*)&A[(long)row * HD + k0 + g * 8];
      acc[i] = __builtin_amdgcn_mfma_f32_16x16x32_bf16(afr, bfr, acc[i], 0, 0, 0);
    }
  }
#pragma unroll
  for (int i = 0; i < MT; ++i)
#pragma unroll
    for (int r = 0; r < 4; ++r) {
      int grow = i * 16 + g * 4 + r;
      if (grow < M) {
        int gcol = n0 + l16;
        float v = acc[i][r];
        if (bias_f) v += bias_f[gcol];
        if (bias_bf) v += bf2f(bias_bf[gcol]);
        if (Cf) {
          long off = cf_scatter ? ((long)(grow >> 3) * (8L * BB * HD) + (long)(grow & 7) * HD + gcol)
                                : ((long)grow * HD + gcol);
          Cf[off] = v;
        }
        if (Cb) Cb[(long)grow * HD + gcol] = __float2bfloat16(v);
      }
    }
}

// ---------------- kqf: q[t][b][d] = feats@Wc + h_t@W_att_in[1024:] + qb
__global__ __launch_bounds__(256) void kqf(const int* __restrict__ ids,
                                           const float* __restrict__ emb,
                                           const float* __restrict__ Wc,
                                           const float* __restrict__ W_att_in,
                                           const float* __restrict__ qb,
                                           const float* __restrict__ h_all,
                                           float* __restrict__ q) {
  int blk = blockIdx.x;
  int b = blk >> 5, tp = blk & 31;
  int tid = threadIdx.x;
  __shared__ float lf[2][768];
  __shared__ float lh[2][1024];
  __shared__ float red[2][2][128];
  for (int u = 0; u < 2; ++u) {
    int t = tp * 2 + u;
    int id = ids[b * SS + t];
    for (int i = tid; i < EMB; i += 256) lf[u][i] = emb[(long)id * EMB + i];
    for (int i = tid; i < HD; i += 256) lh[u][i] = h_all[((long)t * BB + b) * HD + i];
  }
  __syncthreads();
  int d = tid & 127, kh = tid >> 7;
  float acc0 = 0.f, acc1 = 0.f;
  for (int k = kh * 384; k < kh * 384 + 384; ++k) {
    float w = Wc[k * D3 + d];
    acc0 = fmaf(lf[0][k], w, acc0);
    acc1 = fmaf(lf[1][k], w, acc1);
  }
  for (int k = kh * 512; k < kh * 512 + 512; ++k) {
    float w = W_att_in[(HD + k) * D3 + d];
    acc0 = fmaf(lh[0][k], w, acc0);
    acc1 = fmaf(lh[1][k], w, acc1);
  }
  red[0][kh][d] = acc0;
  red[1][kh][d] = acc1;
  __syncthreads();
  if (kh == 0) {
    float base = qb[d];
    int t = tp * 2;
    q[((t)*BB + b) * D3 + d] = red[0][0][d] + red[0][1][d] + base;
    q[((t + 1) * BB + b) * D3 + d] = red[1][0][d] + red[1][1][d] + base;
  }
}

// ---------------- katt: out[b][t][c] = sum_d V[d]*tanh(q[t][b][d] + ctxp[b][c][d])
__global__ __launch_bounds__(256) void katt(const float* __restrict__ q,
                                            const float* __restrict__ ctxp,
                                            const float* __restrict__ V,
                                            float* __restrict__ out) {
  int blk = blockIdx.x;
  int b = blk >> 5, tt = (blk >> 4) & 1, ct = blk & 15;
  int t0 = tt * 32, c0 = ct * 32;
  int tid = threadIdx.x;
  __shared__ float lq[32][128];
  __shared__ float lc[32][132];
  __shared__ float lv[128];
  for (int i = tid; i < 32 * 128; i += 256) {
    int r = i >> 7, d = i & 127;
    lq[r][d] = q[((long)(t0 + r) * BB + b) * D3 + d];
    lc[r][d] = ctxp[((long)b * CTXN + c0 + r) * D3 + d];
  }
  if (tid < 128) lv[tid] = V[tid];
  __syncthreads();
  int cl = tid & 31, tg = tid >> 5;
  float r[4] = {0.f, 0.f, 0.f, 0.f};
  for (int d4 = 0; d4 < 32; ++d4) {
    float4 cv = *reinterpret_cast<const float4*>(&lc[cl][d4 * 4]);
    float4 vv = *reinterpret_cast<const float4*>(&lv[d4 * 4]);
#pragma unroll
    for (int u = 0; u < 4; ++u) {
      int t = tg + u * 8;
      float4 qv = *reinterpret_cast<const float4*>(&lq[t][d4 * 4]);
      r[u] = fmaf(vv.x, fast_tanh(qv.x + cv.x), r[u]);
      r[u] = fmaf(vv.y, fast_tanh(qv.y + cv.y), r[u]);
      r[u] = fmaf(vv.z, fast_tanh(qv.z + cv.z), r[u]);
      r[u] = fmaf(vv.w, fast_tanh(qv.w + cv.w), r[u]);
    }
  }
#pragma unroll
  for (int u = 0; u < 4; ++u) {
    int t = tg + u * 8;
    out[((long)b * SS + (t0 + t)) * CTXN + c0 + cl] = r[u];
  }
  if (blk == 0) {
    for (int i = tid; i < SS * BB; i += 256) out[(long)BB * SS * CTXN + i] = 0.f;
  }
}

extern "C" void kernel_launch(void* const* d_in, const int* in_sizes, int n_in,
                              void* d_out, int out_size, void* d_ws, size_t ws_size,
                              hipStream_t stream) {
  const int* ids = (const int*)d_in[0];
  const float* context = (const float*)d_in[4];
  const float* emb = (const float*)d_in[5];
  const float* W_in = (const float*)d_in[6];
  const float* b_in = (const float*)d_in[7];
  const float* W_s = (const float*)d_in[8];
  const float* b_s = (const float*)d_in[9];
  const float* W_att_in = (const float*)d_in[10];
  const float* b_att_in = (const float*)d_in[11];
  const float* W_att_h = (const float*)d_in[12];
  const float* b_att_h = (const float*)d_in[13];
  const float* V = (const float*)d_in[14];

  float* ws = (float*)d_ws;
  float* Wc = ws;                  // 98304
  float* qb = Wc + 98304;          // 128
  float* q = qb + 128;             // 65536
  float* ctxp = q + 65536;         // 524288
  float* h_all = ctxp + 524288;    // 524288
  __hip_bfloat16* bfp = (__hip_bfloat16*)(h_all + 524288);
  __hip_bfloat16* MaugA = bfp;                      // 1025*1024
  __hip_bfloat16* MaugB = MaugA + 1025 * 1024;      // 1025*1024
  __hip_bfloat16* W1T = MaugB + 1025 * 1024;        // 1024*1024
  __hip_bfloat16* W8T = W1T + 1024 * 1024;          // 1024*1024
  __hip_bfloat16* Gmat = W8T + 1024 * 1024;         // 64*1024
  __hip_bfloat16* Hbuf = Gmat + 64 * 1024;          // 2*64*1024
  float* out = (float*)d_out;

  kcast<<<dim3(257), dim3(256), 0, stream>>>(W_s, b_s, context, b_in, W_att_in,
                                             b_att_in, MaugA, W1T, Gmat, qb);
  // ctx_proj: [4096,1024]@[1024,128] fp32->bf16 MFMA
  gemmbt<true, true><<<dim3(32, 2), dim3(256), 0, stream>>>(
      context, HD, 4096, W_att_h, D3, D3, HD, nullptr, b_att_h, ctxp, nullptr, nullptr);
  // Wc = W_in @ W_att_in[:1024]: [768,1024]@[1024,128]
  gemmbt<true, true><<<dim3(6, 2), dim3(256), 0, stream>>>(
      W_in, HD, EMB, W_att_in, D3, D3, HD, nullptr, nullptr, Wc, nullptr, nullptr);
  // affine squarings: A^2, A^4, A^8 (augmented [W;b], addrow composes bias)
  gemmbt<false, false><<<dim3(9, 16), dim3(256), 0, stream>>>(
      MaugA, HD, 1025, MaugA, HD, HD, HD, MaugA + (long)HD * HD, nullptr, nullptr, MaugB, nullptr);
  gemmbt<false, false><<<dim3(9, 16), dim3(256), 0, stream>>>(
      MaugB, HD, 1025, MaugB, HD, HD, HD, MaugB + (long)HD * HD, nullptr, nullptr, MaugA, nullptr);
  gemmbt<false, false><<<dim3(9, 16), dim3(256), 0, stream>>>(
      MaugA, HD, 1025, MaugA, HD, HD, HD, MaugA + (long)HD * HD, nullptr, nullptr, MaugB, W8T);
  const __hip_bfloat16* b8 = MaugB + (long)HD * HD;
  // checkpoints: g_{k+1} = g_k @ W8 + b8 ; h_all[8k+7] = g_{k+1}
  for (int k = 0; k < 8; ++k) {
    smgemm<1><<<dim3(16), dim3(256), 0, stream>>>(
        Gmat + (long)k * BB * HD, 8, W8T, nullptr, b8,
        h_all + (long)(8 * k + 7) * BB * HD, 0,
        (k < 7) ? (Gmat + (long)(k + 1) * BB * HD) : nullptr);
  }
  // fill: H_r = H_{r-1} @ W + b_s ; scatter rows (k,b) -> h_all[8k + r - 1]
  for (int r = 1; r <= 7; ++r) {
    const __hip_bfloat16* Aprev = (r == 1) ? Gmat : (Hbuf + (long)((r - 1) & 1) * 64 * HD);
    smgemm<4><<<dim3(16), dim3(256), 0, stream>>>(
        Aprev, 64, W1T, b_s, nullptr, h_all + (long)(r - 1) * BB * HD, 1,
        (r < 7) ? (Hbuf + (long)(r & 1) * 64 * HD) : nullptr);
  }
  kqf<<<dim3(256), dim3(256), 0, stream>>>(ids, emb, Wc, W_att_in, qb, h_all, q);
  katt<<<dim3(256), dim3(256), 0, stream>>>(q, ctxp, V, out);
}

// Round 4
// 237.603 us; speedup vs baseline: 2.3875x; 2.3875x over previous
//
#include <hip/hip_runtime.h>
#include <hip/hip_bf16.h>

#define EMB 768
#define HD 1024
#define D3 128
#define CTXN 512
#define BB 8
#define SS 64

typedef __attribute__((ext_vector_type(8))) short short8v;
typedef __attribute__((ext_vector_type(4))) float f32x4;

__device__ __forceinline__ float fast_tanh(float x) {
  float e = __expf(2.f * x);
  return 1.f - 2.f * __builtin_amdgcn_rcpf(e + 1.f);
}
__device__ __forceinline__ float bf2f(__hip_bfloat16 x) { return __bfloat162float(x); }

struct GDesc {
  const void* A; const void* B;
  float* Cf; __hip_bfloat16* Cb;
  const __hip_bfloat16* addrow;   // added to row M-1 only
  const float* bias_f;            // added to all rows (fp32)
  const __hip_bfloat16* bias_bf;  // added to all rows (bf16)
  int M, N, K, lda, ldb;
  int af32, bf32, mtiles, blk0, nblks;
};
struct GBatch { GDesc d[6]; int nd; };

// ---------------- gemmz: generic multi-desc 64x64 MFMA GEMM, BK=64, double-buffered
__global__ __launch_bounds__(256) void gemmz(GBatch bat) {
  int bx = blockIdx.x;
  GDesc d = bat.d[0];
#pragma unroll
  for (int i = 1; i < 6; ++i)
    if (i < bat.nd && bx >= bat.d[i].blk0 && bx < bat.d[i].blk0 + bat.d[i].nblks)
      d = bat.d[i];
  int local = bx - d.blk0;
  int mt = local % d.mtiles, nt = local / d.mtiles;
  int bm0 = mt * 64, bn0 = nt * 64;

  __shared__ __hip_bfloat16 As[2][64][72];  // 144B rows: 16B-aligned, balanced banks
  __shared__ __hip_bfloat16 Bt[2][64][72];  // B transposed [n][k]
  int tid = threadIdx.x;
  int lane = tid & 63, wid = tid >> 6;
  int l16 = lane & 15, g = lane >> 4;
  int wm = wid * 16;
  int arow = tid >> 2, aseg = tid & 3;  // A: 64 rows x 64k, 16 el/thread
  int brow = tid >> 2, bseg = tid & 3;  // B: 64 k-rows x 64n, 16 el/thread
  f32x4 acc[4] = {};
  float fa[16], fb[16];
  short8v ba0 = {}, ba1 = {}, bb0 = {}, bb1 = {};
  int nk = d.K >> 6;

  auto LD = [&](int k0) {
    int gr = bm0 + arow;
    if (d.af32) {
      if (gr < d.M) {
        const float* s = (const float*)d.A + (long)gr * d.lda + k0 + aseg * 16;
#pragma unroll
        for (int j = 0; j < 16; ++j) fa[j] = s[j];
      } else {
#pragma unroll
        for (int j = 0; j < 16; ++j) fa[j] = 0.f;
      }
    } else {
      if (gr < d.M) {
        const __hip_bfloat16* s = (const __hip_bfloat16*)d.A + (long)gr * d.lda + k0 + aseg * 16;
        ba0 = *(const short8v*)s;
        ba1 = *(const short8v*)(s + 8);
      } else {
        short8v z = {};
        ba0 = z; ba1 = z;
      }
    }
    int gk = k0 + brow;
    if (d.bf32) {
      const float* s = (const float*)d.B + (long)gk * d.ldb + bn0 + bseg * 16;
#pragma unroll
      for (int j = 0; j < 16; ++j) fb[j] = s[j];
    } else {
      const __hip_bfloat16* s = (const __hip_bfloat16*)d.B + (long)gk * d.ldb + bn0 + bseg * 16;
      bb0 = *(const short8v*)s;
      bb1 = *(const short8v*)(s + 8);
    }
  };
  auto ST = [&](int buf) {
    __hip_bfloat16 t[16];
    if (d.af32) {
#pragma unroll
      for (int j = 0; j < 16; ++j) t[j] = __float2bfloat16(fa[j]);
    } else {
      *(short8v*)t = ba0;
      *(short8v*)(t + 8) = ba1;
    }
    *(short8v*)&As[buf][arow][aseg * 16] = *(short8v*)t;
    *(short8v*)&As[buf][arow][aseg * 16 + 8] = *(short8v*)(t + 8);
    if (d.bf32) {
#pragma unroll
      for (int j = 0; j < 16; ++j) t[j] = __float2bfloat16(fb[j]);
    } else {
      *(short8v*)t = bb0;
      *(short8v*)(t + 8) = bb1;
    }
#pragma unroll
    for (int j = 0; j < 16; ++j) Bt[buf][bseg * 16 + j][brow] = t[j];
  };

  LD(0);
  ST(0);
  __syncthreads();
  for (int it = 0; it < nk; ++it) {
    int cur = it & 1;
    if (it + 1 < nk) LD((it + 1) << 6);
#pragma unroll
    for (int kf = 0; kf < 2; ++kf) {
      short8v a = *(const short8v*)&As[cur][wm + l16][kf * 32 + g * 8];
#pragma unroll
      for (int j = 0; j < 4; ++j) {
        short8v b = *(const short8v*)&Bt[cur][j * 16 + l16][kf * 32 + g * 8];
        acc[j] = __builtin_amdgcn_mfma_f32_16x16x32_bf16(a, b, acc[j], 0, 0, 0);
      }
    }
    if (it + 1 < nk) ST(cur ^ 1);
    __syncthreads();
  }

#pragma unroll
  for (int j = 0; j < 4; ++j)
#pragma unroll
    for (int r = 0; r < 4; ++r) {
      int grow = bm0 + wm + g * 4 + r;
      int gcol = bn0 + j * 16 + l16;
      if (grow < d.M) {
        float v = acc[j][r];
        if (d.bias_f) v += d.bias_f[gcol];
        if (d.bias_bf) v += bf2f(d.bias_bf[gcol]);
        if (d.addrow && grow == d.M - 1) v += bf2f(d.addrow[gcol]);
        if (d.Cf) d.Cf[(long)grow * d.N + gcol] = v;
        if (d.Cb) d.Cb[(long)grow * d.N + gcol] = __float2bfloat16(v);
      }
    }
}

// ---------------- kcast: Maug1 bf16, Y0 bf16 (=[Wa_h;0]), g0 (bf16+fp32), qb
__global__ __launch_bounds__(256) void kcast(const float* __restrict__ W_s,
                                             const float* __restrict__ b_s,
                                             const float* __restrict__ context,
                                             const float* __restrict__ b_in,
                                             const float* __restrict__ W_att_in,
                                             const float* __restrict__ b_att_in,
                                             __hip_bfloat16* __restrict__ Maug1,
                                             __hip_bfloat16* __restrict__ Yb0,
                                             __hip_bfloat16* __restrict__ Gb,
                                             float* __restrict__ gf,
                                             float* __restrict__ qb) {
  int blk = blockIdx.x, tid = threadIdx.x;
  if (blk < 256) {
    int base = blk * 4096;
    for (int i = tid; i < 4096; i += 256)
      Maug1[base + i] = __float2bfloat16(W_s[base + i]);
    return;
  }
  if (blk == 256) {
    __shared__ float red[2][128];
    int d = tid & 127, h = tid >> 7;
    float acc = 0.f;
    for (int k = h * 512; k < h * 512 + 512; ++k) acc += b_in[k] * W_att_in[k * D3 + d];
    red[h][d] = acc;
    __syncthreads();
    if (h == 0) qb[d] = red[0][d] + red[1][d] + b_att_in[d];
    for (int i = tid; i < HD; i += 256) Maug1[1048576 + i] = __float2bfloat16(b_s[i]);
    return;
  }
  if (blk <= 260) {
    int r0 = (blk - 257) * 256;
    for (int i = tid; i < 256 * 128; i += 256) {
      int r = r0 + (i >> 7), dd = i & 127;
      Yb0[r * 128 + dd] = __float2bfloat16(W_att_in[(1024 + r) * D3 + dd]);
    }
    if (blk == 257)
      for (int i = tid; i < 128; i += 256) Yb0[131072 + i] = __float2bfloat16(0.f);
    return;
  }
  // blk 261: g0 = context[:, -1, :]
  for (int i = tid; i < 8192; i += 256) {
    int b = i >> 10, k = i & 1023;
    float v = context[((long)b * CTXN + CTXN - 1) * HD + k];
    Gb[i] = __float2bfloat16(v);
    gf[i] = v;
  }
}

// ---------------- kqf: q[t,b,d] = qb + feats@Wc + g_{t>>3}@Z_{r'} + c_{r'},  r'=(t&7)+1
__global__ __launch_bounds__(256) void kqf(const int* __restrict__ ids,
                                           const float* __restrict__ emb,
                                           const float* __restrict__ Wc,
                                           const float* __restrict__ Yf,
                                           const float* __restrict__ gf,
                                           const float* __restrict__ qb,
                                           float* __restrict__ q) {
  int blk = blockIdx.x;
  int b = blk >> 5, tp = blk & 31;
  int tid = threadIdx.x;
  __shared__ float lf[2][768];
  __shared__ float lh[2][1024];
  __shared__ float red[2][2][128];
  for (int u = 0; u < 2; ++u) {
    int t = tp * 2 + u;
    int id = ids[b * SS + t];
    for (int i = tid; i < EMB; i += 256) lf[u][i] = emb[(long)id * EMB + i];
    int kp = t >> 3;
    for (int i = tid; i < HD; i += 256) lh[u][i] = gf[kp * 8192 + b * 1024 + i];
  }
  __syncthreads();
  int d = tid & 127, kh = tid >> 7;
  int t0 = tp * 2, t1 = tp * 2 + 1;
  const float* Y0 = Yf + (long)((t0 & 7) + 1) * 131200;
  const float* Y1 = Yf + (long)((t1 & 7) + 1) * 131200;
  float acc0 = 0.f, acc1 = 0.f;
  for (int k = kh * 384; k < kh * 384 + 384; ++k) {
    float w = Wc[k * 128 + d];
    acc0 = fmaf(lf[0][k], w, acc0);
    acc1 = fmaf(lf[1][k], w, acc1);
  }
  for (int k = kh * 512; k < kh * 512 + 512; ++k) {
    acc0 = fmaf(lh[0][k], Y0[k * 128 + d], acc0);
    acc1 = fmaf(lh[1][k], Y1[k * 128 + d], acc1);
  }
  red[0][kh][d] = acc0;
  red[1][kh][d] = acc1;
  __syncthreads();
  if (kh == 0) {
    float base = qb[d];
    q[(t0 * BB + b) * D3 + d] = red[0][0][d] + red[0][1][d] + base + Y0[131072 + d];
    q[(t1 * BB + b) * D3 + d] = red[1][0][d] + red[1][1][d] + base + Y1[131072 + d];
  }
}

// ---------------- katt: out[b][t][c] = sum_d V[d]*tanh(q[t][b][d] + ctxp[b][c][d])
__global__ __launch_bounds__(256) void katt(const float* __restrict__ q,
                                            const float* __restrict__ ctxp,
                                            const float* __restrict__ V,
                                            float* __restrict__ out) {
  int blk = blockIdx.x;
  int b = blk >> 5, tt = (blk >> 4) & 1, ct = blk & 15;
  int t0 = tt * 32, c0 = ct * 32;
  int tid = threadIdx.x;
  __shared__ float lq[32][128];
  __shared__ float lc[32][132];
  __shared__ float lv[128];
  for (int i = tid; i < 32 * 128; i += 256) {
    int r = i >> 7, d = i & 127;
    lq[r][d] = q[((long)(t0 + r) * BB + b) * D3 + d];
    lc[r][d] = ctxp[((long)b * CTXN + c0 + r) * D3 + d];
  }
  if (tid < 128) lv[tid] = V[tid];
  __syncthreads();
  int cl = tid & 31, tg = tid >> 5;
  float r[4] = {0.f, 0.f, 0.f, 0.f};
  for (int d4 = 0; d4 < 32; ++d4) {
    float4 cv = *reinterpret_cast<const float4*>(&lc[cl][d4 * 4]);
    float4 vv = *reinterpret_cast<const float4*>(&lv[d4 * 4]);
#pragma unroll
    for (int u = 0; u < 4; ++u) {
      int t = tg + u * 8;
      float4 qv = *reinterpret_cast<const float4*>(&lq[t][d4 * 4]);
      r[u] = fmaf(vv.x, fast_tanh(qv.x + cv.x), r[u]);
      r[u] = fmaf(vv.y, fast_tanh(qv.y + cv.y), r[u]);
      r[u] = fmaf(vv.z, fast_tanh(qv.z + cv.z), r[u]);
      r[u] = fmaf(vv.w, fast_tanh(qv.w + cv.w), r[u]);
    }
  }
#pragma unroll
  for (int u = 0; u < 4; ++u) {
    int t = tg + u * 8;
    out[((long)b * SS + (t0 + t)) * CTXN + c0 + cl] = r[u];
  }
  if (blk == 0) {
    for (int i = tid; i < SS * BB; i += 256) out[(long)BB * SS * CTXN + i] = 0.f;
  }
}

static inline GDesc mk(const void* A, const void* B, float* Cf, __hip_bfloat16* Cb,
                       const __hip_bfloat16* addrow, const float* bias_f,
                       const __hip_bfloat16* bias_bf, int M, int N, int K, int lda,
                       int ldb, int af32, int bf32, int blk0) {
  GDesc d;
  d.A = A; d.B = B; d.Cf = Cf; d.Cb = Cb;
  d.addrow = addrow; d.bias_f = bias_f; d.bias_bf = bias_bf;
  d.M = M; d.N = N; d.K = K; d.lda = lda; d.ldb = ldb;
  d.af32 = af32; d.bf32 = bf32;
  d.mtiles = (M + 63) >> 6; d.blk0 = blk0; d.nblks = d.mtiles * (N >> 6);
  return d;
}

extern "C" void kernel_launch(void* const* d_in, const int* in_sizes, int n_in,
                              void* d_out, int out_size, void* d_ws, size_t ws_size,
                              hipStream_t stream) {
  const int* ids = (const int*)d_in[0];
  const float* context = (const float*)d_in[4];
  const float* emb = (const float*)d_in[5];
  const float* W_in = (const float*)d_in[6];
  const float* b_in = (const float*)d_in[7];
  const float* W_s = (const float*)d_in[8];
  const float* b_s = (const float*)d_in[9];
  const float* W_att_in = (const float*)d_in[10];
  const float* b_att_in = (const float*)d_in[11];
  const float* W_att_h = (const float*)d_in[12];
  const float* b_att_h = (const float*)d_in[13];
  const float* V = (const float*)d_in[14];

  float* ws = (float*)d_ws;
  float* Wc = ws;                       // 98304
  float* qb = Wc + 98304;               // 128
  float* q = qb + 128;                  // 65536
  float* ctxp = q + 65536;              // 524288
  float* Yf = ctxp + 524288;            // 9*131200 = 1180800
  float* gf = Yf + 1180800;             // 9*8192 = 73728
  __hip_bfloat16* bfp = (__hip_bfloat16*)(gf + 73728);
  __hip_bfloat16* Mb0 = bfp;            // 1025*1024
  __hip_bfloat16* Mb1 = Mb0 + 1049600;
  __hip_bfloat16* Mb2 = Mb1 + 1049600;
  __hip_bfloat16* Yb = Mb2 + 1049600;   // 9*131200
  __hip_bfloat16* Gb = Yb + 1180800;    // 9*8192
  float* out = (float*)d_out;

  auto Ybr = [&](int r) { return Yb + (long)r * 131200; };
  auto Yfr = [&](int r) { return Yf + (long)r * 131200; };
  const int MB = 1024 * 1024;  // bias-row offset in Maug

  kcast<<<dim3(262), dim3(256), 0, stream>>>(W_s, b_s, context, b_in, W_att_in,
                                             b_att_in, Mb0, Ybr(0), Gb, gf, qb);
  // L1: Maug2, Y1, ctx_proj, Wc
  {
    GBatch bt{}; int c = 0;
    bt.d[0] = mk(Mb0, Mb0, nullptr, Mb1, Mb0 + MB, nullptr, nullptr, 1025, 1024, 1024, 1024, 1024, 0, 0, c); c += bt.d[0].nblks;
    bt.d[1] = mk(Mb0, Ybr(0), Yfr(1), Ybr(1), Ybr(0) + 131072, nullptr, nullptr, 1025, 128, 1024, 1024, 128, 0, 0, c); c += bt.d[1].nblks;
    bt.d[2] = mk(context, W_att_h, ctxp, nullptr, nullptr, b_att_h, nullptr, 4096, 128, 1024, 1024, 128, 1, 1, c); c += bt.d[2].nblks;
    bt.d[3] = mk(W_in, W_att_in, Wc, nullptr, nullptr, nullptr, nullptr, 768, 128, 1024, 1024, 128, 1, 1, c); c += bt.d[3].nblks;
    bt.nd = 4;
    gemmz<<<dim3(c), dim3(256), 0, stream>>>(bt);
  }
  // L2: Maug4, Y2, Y3
  {
    GBatch bt{}; int c = 0;
    bt.d[0] = mk(Mb1, Mb1, nullptr, Mb2, Mb1 + MB, nullptr, nullptr, 1025, 1024, 1024, 1024, 1024, 0, 0, c); c += bt.d[0].nblks;
    bt.d[1] = mk(Mb1, Ybr(0), Yfr(2), Ybr(2), Ybr(0) + 131072, nullptr, nullptr, 1025, 128, 1024, 1024, 128, 0, 0, c); c += bt.d[1].nblks;
    bt.d[2] = mk(Mb1, Ybr(1), Yfr(3), Ybr(3), Ybr(1) + 131072, nullptr, nullptr, 1025, 128, 1024, 1024, 128, 0, 0, c); c += bt.d[2].nblks;
    bt.nd = 3;
    gemmz<<<dim3(c), dim3(256), 0, stream>>>(bt);
  }
  // L3: Maug8, Y4..Y7
  {
    GBatch bt{}; int c = 0;
    bt.d[0] = mk(Mb2, Mb2, nullptr, Mb0, Mb2 + MB, nullptr, nullptr, 1025, 1024, 1024, 1024, 1024, 0, 0, c); c += bt.d[0].nblks;
    for (int s = 0; s < 4; ++s) {
      bt.d[1 + s] = mk(Mb2, Ybr(s), Yfr(4 + s), Ybr(4 + s), Ybr(s) + 131072, nullptr, nullptr, 1025, 128, 1024, 1024, 128, 0, 0, c);
      c += bt.d[1 + s].nblks;
    }
    bt.nd = 5;
    gemmz<<<dim3(c), dim3(256), 0, stream>>>(bt);
  }
  // L4: Maug16, Y8, g1
  {
    GBatch bt{}; int c = 0;
    bt.d[0] = mk(Mb0, Mb0, nullptr, Mb1, Mb0 + MB, nullptr, nullptr, 1025, 1024, 1024, 1024, 1024, 0, 0, c); c += bt.d[0].nblks;
    bt.d[1] = mk(Mb0, Ybr(0), Yfr(8), Ybr(8), Ybr(0) + 131072, nullptr, nullptr, 1025, 128, 1024, 1024, 128, 0, 0, c); c += bt.d[1].nblks;
    bt.d[2] = mk(Gb, Mb0, gf + 8192, Gb + 8192, nullptr, nullptr, Mb0 + MB, 8, 1024, 1024, 1024, 1024, 0, 0, c); c += bt.d[2].nblks;
    bt.nd = 3;
    gemmz<<<dim3(c), dim3(256), 0, stream>>>(bt);
  }
  // L5: Maug32, [g2,g3]
  {
    GBatch bt{}; int c = 0;
    bt.d[0] = mk(Mb1, Mb1, nullptr, Mb2, Mb1 + MB, nullptr, nullptr, 1025, 1024, 1024, 1024, 1024, 0, 0, c); c += bt.d[0].nblks;
    bt.d[1] = mk(Gb, Mb1, gf + 16384, Gb + 16384, nullptr, nullptr, Mb1 + MB, 16, 1024, 1024, 1024, 1024, 0, 0, c); c += bt.d[1].nblks;
    bt.nd = 2;
    gemmz<<<dim3(c), dim3(256), 0, stream>>>(bt);
  }
  // L6: [g4..g7]
  {
    GBatch bt{}; int c = 0;
    bt.d[0] = mk(Gb, Mb2, gf + 32768, Gb + 32768, nullptr, nullptr, Mb2 + MB, 32, 1024, 1024, 1024, 1024, 0, 0, c); c += bt.d[0].nblks;
    bt.nd = 1;
    gemmz<<<dim3(c), dim3(256), 0, stream>>>(bt);
  }
  kqf<<<dim3(256), dim3(256), 0, stream>>>(ids, emb, Wc, Yf, gf, qb, q);
  katt<<<dim3(256), dim3(256), 0, stream>>>(q, ctxp, V, out);
}

// Round 5
// 159.213 us; speedup vs baseline: 3.5631x; 1.4924x over previous
//
#include <hip/hip_runtime.h>
#include <hip/hip_bf16.h>

#define EMB 768
#define HD 1024
#define D3 128
#define CTXN 512
#define BB 8
#define SS 64

typedef __attribute__((ext_vector_type(8))) short short8v;
typedef __attribute__((ext_vector_type(4))) float f32x4;

__device__ __forceinline__ float fast_tanh(float x) {
  float e = __expf(2.f * x);
  return 1.f - 2.f * __builtin_amdgcn_rcpf(e + 1.f);
}
__device__ __forceinline__ float bf2f(__hip_bfloat16 x) { return __bfloat162float(x); }

struct GDesc {
  const void* A;                 // row-major [M][K], fp32 or bf16
  const __hip_bfloat16* BT;      // transposed B: [N][K] bf16
  const int* arowmap;            // optional A row gather
  const float* addrow_f;         // added to row M-1 only (affine-aug compose)
  const float* bias_f;           // added to all rows
  float* Cf;                     // fp32 row-major out
  __hip_bfloat16* Cb;            // bf16 row-major out
  __hip_bfloat16* CbT;           // bf16 transposed out [N][ldct], rows<1024 only
  float* brow_f;                 // fp32 copy of row M-1
  int M, N, K, lda, ldbt, ldct, af32, mtiles, blk0, nblks;
};
struct GBatch { GDesc d[10]; int nd; };

// gemmz: 32x64 tile, BK=64, 4 waves (each 16x32), XOR-swizzled LDS, dbuf.
__global__ __launch_bounds__(256) void gemmz(GBatch bat) {
  int bx = blockIdx.x;
  GDesc d = bat.d[0];
  for (int i = 1; i < bat.nd; ++i)
    if (bx >= bat.d[i].blk0) d = bat.d[i];
  int local = bx - d.blk0;
  int mt = local % d.mtiles, nt = local / d.mtiles;
  int bm0 = mt * 32, bn0 = nt * 64;

  __shared__ __hip_bfloat16 As[2][32][64];  // swizzled: chunk^(row&7)
  __shared__ __hip_bfloat16 Bs[2][64][64];
  int tid = threadIdx.x, lane = tid & 63, wid = tid >> 6;
  int l16 = lane & 15, g = lane >> 4;
  int wm = (wid & 1) * 16, wn = (wid >> 1) * 32;
  int arow = tid >> 3, aseg = tid & 7;  // A: 32 rows x 8 chunks
  int brow = tid >> 2, bseg = tid & 3;  // B: 64 rows x chunks {2b,2b+1}
  f32x4 acc[2] = {};

  int agr = bm0 + arow;
  int asrc = (agr < d.M) ? (d.arowmap ? d.arowmap[agr] : agr) : -1;
  const float* Af = (const float*)d.A;
  const __hip_bfloat16* Ab = (const __hip_bfloat16*)d.A;

  float fa[8];
  short8v ba = {}, bb0 = {}, bb1 = {};
  int nk = d.K >> 6;

  auto LD = [&](int k0) {
    if (d.af32) {
      if (asrc >= 0) {
        const float* s = Af + (long)asrc * d.lda + k0 + aseg * 8;
#pragma unroll
        for (int j = 0; j < 8; ++j) fa[j] = s[j];
      } else {
#pragma unroll
        for (int j = 0; j < 8; ++j) fa[j] = 0.f;
      }
    } else {
      if (asrc >= 0)
        ba = *(const short8v*)(Ab + (long)asrc * d.lda + k0 + aseg * 8);
      else {
        short8v z = {};
        ba = z;
      }
    }
    const __hip_bfloat16* bsrc = d.BT + (long)(bn0 + brow) * d.ldbt + k0 + bseg * 16;
    bb0 = *(const short8v*)bsrc;
    bb1 = *(const short8v*)(bsrc + 8);
  };
  auto ST = [&](int buf) {
    __hip_bfloat16 t8[8];
    if (d.af32) {
#pragma unroll
      for (int j = 0; j < 8; ++j) t8[j] = __float2bfloat16(fa[j]);
      *(short8v*)&As[buf][arow][(aseg ^ (arow & 7)) * 8] = *(short8v*)t8;
    } else {
      *(short8v*)&As[buf][arow][(aseg ^ (arow & 7)) * 8] = ba;
    }
    *(short8v*)&Bs[buf][brow][((2 * bseg) ^ (brow & 7)) * 8] = bb0;
    *(short8v*)&Bs[buf][brow][((2 * bseg + 1) ^ (brow & 7)) * 8] = bb1;
  };

  LD(0);
  ST(0);
  __syncthreads();
  for (int it = 0; it < nk; ++it) {
    int cur = it & 1;
    if (it + 1 < nk) LD((it + 1) << 6);
#pragma unroll
    for (int kf = 0; kf < 2; ++kf) {
      int ar = wm + l16;
      short8v a = *(const short8v*)&As[cur][ar][(((kf << 2) | g) ^ (ar & 7)) * 8];
#pragma unroll
      for (int j = 0; j < 2; ++j) {
        int br = wn + j * 16 + l16;
        short8v b = *(const short8v*)&Bs[cur][br][(((kf << 2) | g) ^ (br & 7)) * 8];
        acc[j] = __builtin_amdgcn_mfma_f32_16x16x32_bf16(a, b, acc[j], 0, 0, 0);
      }
    }
    if (it + 1 < nk) ST(cur ^ 1);
    __syncthreads();
  }

  // epilogue (loop-end sync already passed: LDS free)
  float* Cs = (float*)&Bs[0][0][0];  // [64][33] floats = 8448B <= 16KB
  bool doT = (d.CbT != nullptr);
#pragma unroll
  for (int j = 0; j < 2; ++j)
#pragma unroll
    for (int r = 0; r < 4; ++r) {
      int gl = wm + g * 4 + r, cl = wn + j * 16 + l16;
      int grow = bm0 + gl, gcol = bn0 + cl;
      float v = acc[j][r];
      if (d.bias_f) v += d.bias_f[gcol];
      if (d.addrow_f && grow == d.M - 1) v += d.addrow_f[gcol];
      if (grow < d.M) {
        if (d.Cf) d.Cf[(long)grow * d.N + gcol] = v;
        if (d.Cb) d.Cb[(long)grow * d.N + gcol] = __float2bfloat16(v);
        if (d.brow_f && grow == d.M - 1) d.brow_f[gcol] = v;
      }
      if (doT) Cs[cl * 33 + gl] = v;
    }
  if (doT) {
    __syncthreads();
    int ctrows = d.M < 1024 ? d.M : 1024;
    int n = tid >> 2, ms = (tid & 3) * 8;
    int gm0 = bm0 + ms;
    __hip_bfloat16 t8[8];
#pragma unroll
    for (int jj = 0; jj < 8; ++jj) t8[jj] = __float2bfloat16(Cs[n * 33 + ms + jj]);
    if (gm0 + 7 < ctrows) {
      *(short8v*)&d.CbT[(long)(bn0 + n) * d.ldct + gm0] = *(short8v*)t8;
    } else {
#pragma unroll
      for (int jj = 0; jj < 8; ++jj)
        if (gm0 + jj < ctrows) d.CbT[(long)(bn0 + n) * d.ldct + gm0 + jj] = t8[jj];
    }
  }
}

// kcast: Maug1 bf16, transposes (W_s^T, Wa_bot^T, Wah^T, Wa_top^T), g0, qb, rowmap
__global__ __launch_bounds__(256) void kcast(const float* __restrict__ W_s,
                                             const float* __restrict__ b_s,
                                             const float* __restrict__ context,
                                             const float* __restrict__ b_in,
                                             const float* __restrict__ W_att_in,
                                             const float* __restrict__ b_att_in,
                                             const float* __restrict__ W_att_h,
                                             const int* __restrict__ ids,
                                             __hip_bfloat16* __restrict__ Mb0,
                                             __hip_bfloat16* __restrict__ Mb0T,
                                             __hip_bfloat16* __restrict__ Y0T,
                                             __hip_bfloat16* __restrict__ WahT,
                                             __hip_bfloat16* __restrict__ WaiT,
                                             __hip_bfloat16* __restrict__ Gb,
                                             float* __restrict__ qb,
                                             int* __restrict__ rowmap) {
  int blk = blockIdx.x, tid = threadIdx.x;
  __shared__ __hip_bfloat16 tl[64][65];
  __shared__ float red[2][128];

  auto TP = [&](const float* src, int R, int C, __hip_bfloat16* dst, int tr, int tc) {
    int r0 = tr * 64, c0 = tc * 64;
    {
      int r = tid >> 2, cs = (tid & 3) * 16;
      const float* s = src + (long)(r0 + r) * C + c0 + cs;
#pragma unroll
      for (int j = 0; j < 16; ++j) tl[cs + j][r] = __float2bfloat16(s[j]);
    }
    __syncthreads();
    {
      int c = tid >> 2, rs = (tid & 3) * 16;
      __hip_bfloat16 o[16];
#pragma unroll
      for (int j = 0; j < 16; ++j) o[j] = tl[c][rs + j];
      *(short8v*)&dst[(long)(c0 + c) * R + r0 + rs] = *(short8v*)&o[0];
      *(short8v*)&dst[(long)(c0 + c) * R + r0 + rs + 8] = *(short8v*)&o[8];
    }
  };

  if (blk < 256) {
    long base = (long)blk * 4096;
    for (int i = tid; i < 4096; i += 256)
      Mb0[base + i] = __float2bfloat16(W_s[base + i]);
  } else if (blk == 256) {
    for (int i = tid; i < HD; i += 256)
      Mb0[(long)HD * HD + i] = __float2bfloat16(b_s[i]);
  } else if (blk < 513) {
    int t = blk - 257;
    TP(W_s, 1024, 1024, Mb0T, t >> 4, t & 15);
  } else if (blk < 545) {
    int t = blk - 513;
    TP(W_att_in + (long)1024 * D3, 1024, 128, Y0T, t >> 1, t & 1);
  } else if (blk < 577) {
    int t = blk - 545;
    TP(W_att_h, 1024, 128, WahT, t >> 1, t & 1);
  } else if (blk < 609) {
    int t = blk - 577;
    TP(W_att_in, 1024, 128, WaiT, t >> 1, t & 1);
  } else if (blk == 609) {
    for (int i = tid; i < BB * HD; i += 256) {
      int b = i >> 10, k = i & 1023;
      Gb[i] = __float2bfloat16(context[((long)b * CTXN + CTXN - 1) * HD + k]);
    }
  } else if (blk == 610) {
    int dd = tid & 127, h = tid >> 7;
    float acc = 0.f;
    for (int k = h * 512; k < h * 512 + 512; ++k)
      acc += b_in[k] * W_att_in[k * D3 + dd];
    red[h][dd] = acc;
    __syncthreads();
    if (h == 0) qb[dd] = red[0][dd] + red[1][dd] + b_att_in[dd];
  } else {
    for (int i = tid; i < 512; i += 256) {
      int t = i >> 3, b = i & 7;
      rowmap[i] = ids[b * SS + t];
    }
  }
}

// katt: out[b][t][c] = sum_d V[d]*tanh(qF[t*8+b][d] + qH[t&7][(t>>3)*8+b][d] + ctxp[b][c][d])
__global__ __launch_bounds__(256) void katt(const float* __restrict__ qF,
                                            const float* __restrict__ qH,
                                            const float* __restrict__ ctxp,
                                            const float* __restrict__ V,
                                            float* __restrict__ out) {
  int blk = blockIdx.x;
  int b = blk >> 5, tt = (blk >> 4) & 1, ct = blk & 15;
  int t0 = tt * 32, c0 = ct * 32;
  int tid = threadIdx.x;
  __shared__ float lq[32][128];
  __shared__ float lc[32][132];
  __shared__ float lv[128];
  for (int i = tid; i < 32 * 128; i += 256) {
    int r = i >> 7, d = i & 127;
    int t = t0 + r;
    lq[r][d] = qF[((long)t * 8 + b) * 128 + d] +
               qH[(((long)(t & 7)) * 64 + (t >> 3) * 8 + b) * 128 + d];
    lc[r][d] = ctxp[((long)b * CTXN + c0 + r) * D3 + d];
  }
  if (tid < 128) lv[tid] = V[tid];
  __syncthreads();
  int cl = tid & 31, tg = tid >> 5;
  float r[4] = {0.f, 0.f, 0.f, 0.f};
  for (int d4 = 0; d4 < 32; ++d4) {
    float4 cv = *reinterpret_cast<const float4*>(&lc[cl][d4 * 4]);
    float4 vv = *reinterpret_cast<const float4*>(&lv[d4 * 4]);
#pragma unroll
    for (int u = 0; u < 4; ++u) {
      int t = tg + u * 8;
      float4 qv = *reinterpret_cast<const float4*>(&lq[t][d4 * 4]);
      r[u] = fmaf(vv.x, fast_tanh(qv.x + cv.x), r[u]);
      r[u] = fmaf(vv.y, fast_tanh(qv.y + cv.y), r[u]);
      r[u] = fmaf(vv.z, fast_tanh(qv.z + cv.z), r[u]);
      r[u] = fmaf(vv.w, fast_tanh(qv.w + cv.w), r[u]);
    }
  }
#pragma unroll
  for (int u = 0; u < 4; ++u) {
    int t = tg + u * 8;
    out[((long)b * SS + (t0 + t)) * CTXN + c0 + cl] = r[u];
  }
  if (blk == 0) {
    for (int i = tid; i < SS * BB; i += 256) out[(long)BB * SS * CTXN + i] = 0.f;
  }
}

static inline GDesc mk(const void* A, int af32, int lda, const int* arowmap,
                       const __hip_bfloat16* BT, int ldbt, int M, int N, int K,
                       const float* addrow_f, const float* bias_f, float* Cf,
                       __hip_bfloat16* Cb, __hip_bfloat16* CbT, int ldct,
                       float* brow_f, int blk0) {
  GDesc d;
  d.A = A; d.BT = BT; d.arowmap = arowmap;
  d.addrow_f = addrow_f; d.bias_f = bias_f;
  d.Cf = Cf; d.Cb = Cb; d.CbT = CbT; d.brow_f = brow_f;
  d.M = M; d.N = N; d.K = K; d.lda = lda; d.ldbt = ldbt; d.ldct = ldct;
  d.af32 = af32;
  d.mtiles = (M + 31) >> 5;
  d.blk0 = blk0;
  d.nblks = d.mtiles * (N >> 6);
  return d;
}

extern "C" void kernel_launch(void* const* d_in, const int* in_sizes, int n_in,
                              void* d_out, int out_size, void* d_ws, size_t ws_size,
                              hipStream_t stream) {
  const int* ids = (const int*)d_in[0];
  const float* context = (const float*)d_in[4];
  const float* emb = (const float*)d_in[5];
  const float* W_in = (const float*)d_in[6];
  const float* b_in = (const float*)d_in[7];
  const float* W_s = (const float*)d_in[8];
  const float* b_s = (const float*)d_in[9];
  const float* W_att_in = (const float*)d_in[10];
  const float* b_att_in = (const float*)d_in[11];
  const float* W_att_h = (const float*)d_in[12];
  const float* b_att_h = (const float*)d_in[13];
  const float* V = (const float*)d_in[14];

  float* ws = (float*)d_ws;
  float* ctxp = ws;                     // 524288
  float* Yf = ctxp + 524288;            // 9*131200 (slot r, r=0 unused)
  float* qF = Yf + 1180800;             // 65536
  float* qH = qF + 65536;               // 8*64*128 = 65536
  float* qb = qH + 65536;               // 128
  float* brow2 = qb + 128;              // 1024 each
  float* brow4 = brow2 + 1024;
  float* brow8 = brow4 + 1024;
  float* brow16 = brow8 + 1024;
  float* brow32 = brow16 + 1024;
  int* rowmap = (int*)(brow32 + 1024);  // 512
  __hip_bfloat16* bfp = (__hip_bfloat16*)(rowmap + 512);
  __hip_bfloat16* Mb0 = bfp;            // 1025*1024
  __hip_bfloat16* Mb0T = Mb0 + 1049600; // 1024*1024
  __hip_bfloat16* Mb1 = Mb0T + 1048576;
  __hip_bfloat16* Mb1T = Mb1 + 1049600;
  __hip_bfloat16* Mb2 = Mb1T + 1048576;
  __hip_bfloat16* Mb2T = Mb2 + 1049600;
  __hip_bfloat16* Mb3 = Mb2T + 1048576;
  __hip_bfloat16* Mb3T = Mb3 + 1049600;
  __hip_bfloat16* YT = Mb3T + 1048576;  // 9 slots * 131072
  __hip_bfloat16* WahT = YT + 9 * 131072;
  __hip_bfloat16* WaiT = WahT + 131072;
  __hip_bfloat16* WcT = WaiT + 131072;  // [128][768]
  __hip_bfloat16* Gb = WcT + 131072;    // 64*1024
  float* out = (float*)d_out;

  auto Yfr = [&](int r) { return Yf + (long)r * 131200; };
  auto YTs = [&](int r) { return YT + (long)r * 131072; };

  kcast<<<dim3(612), dim3(256), 0, stream>>>(W_s, b_s, context, b_in, W_att_in,
                                             b_att_in, W_att_h, ids, Mb0, Mb0T,
                                             YTs(0), WahT, WaiT, Gb, qb, rowmap);
  // L1: M2 = M1^2 ; Y1 = M1*Y0 ; ctx_proj ; Wc
  {
    GBatch bt{}; int c = 0;
    bt.d[0] = mk(Mb0, 0, 1024, nullptr, Mb0T, 1024, 1025, 1024, 1024, b_s, nullptr, nullptr, Mb1, Mb1T, 1024, brow2, c); c += bt.d[0].nblks;
    bt.d[1] = mk(Mb0, 0, 1024, nullptr, YTs(0), 1024, 1025, 128, 1024, nullptr, nullptr, Yfr(1), nullptr, YTs(1), 1024, nullptr, c); c += bt.d[1].nblks;
    bt.d[2] = mk(context, 1, 1024, nullptr, WahT, 1024, 4096, 128, 1024, nullptr, b_att_h, ctxp, nullptr, nullptr, 0, nullptr, c); c += bt.d[2].nblks;
    bt.d[3] = mk(W_in, 1, 1024, nullptr, WaiT, 1024, 768, 128, 1024, nullptr, nullptr, nullptr, nullptr, WcT, 768, nullptr, c); c += bt.d[3].nblks;
    bt.nd = 4;
    gemmz<<<dim3(c), dim3(256), 0, stream>>>(bt);
  }
  // L2: M4 ; Y2 = M2*Y0 ; Y3 = M2∘Y1
  {
    GBatch bt{}; int c = 0;
    bt.d[0] = mk(Mb1, 0, 1024, nullptr, Mb1T, 1024, 1025, 1024, 1024, brow2, nullptr, nullptr, Mb2, Mb2T, 1024, brow4, c); c += bt.d[0].nblks;
    bt.d[1] = mk(Mb1, 0, 1024, nullptr, YTs(0), 1024, 1025, 128, 1024, nullptr, nullptr, Yfr(2), nullptr, YTs(2), 1024, nullptr, c); c += bt.d[1].nblks;
    bt.d[2] = mk(Mb1, 0, 1024, nullptr, YTs(1), 1024, 1025, 128, 1024, Yfr(1) + 131072, nullptr, Yfr(3), nullptr, YTs(3), 1024, nullptr, c); c += bt.d[2].nblks;
    bt.nd = 3;
    gemmz<<<dim3(c), dim3(256), 0, stream>>>(bt);
  }
  // L3: M8 ; Y4..Y7 = M4∘Y0..Y3
  {
    GBatch bt{}; int c = 0;
    bt.d[0] = mk(Mb2, 0, 1024, nullptr, Mb2T, 1024, 1025, 1024, 1024, brow4, nullptr, nullptr, Mb3, Mb3T, 1024, brow8, c); c += bt.d[0].nblks;
    for (int s = 0; s < 4; ++s) {
      bt.d[1 + s] = mk(Mb2, 0, 1024, nullptr, YTs(s), 1024, 1025, 128, 1024,
                       (s == 0) ? nullptr : (Yfr(s) + 131072), nullptr,
                       Yfr(4 + s), nullptr, YTs(4 + s), 1024, nullptr, c);
      c += bt.d[1 + s].nblks;
    }
    bt.nd = 5;
    gemmz<<<dim3(c), dim3(256), 0, stream>>>(bt);
  }
  // L4: M16 ; Y8 = M8*Y0 ; g1 = g0*W8 + b8
  {
    GBatch bt{}; int c = 0;
    bt.d[0] = mk(Mb3, 0, 1024, nullptr, Mb3T, 1024, 1025, 1024, 1024, brow8, nullptr, nullptr, Mb1, Mb1T, 1024, brow16, c); c += bt.d[0].nblks;
    bt.d[1] = mk(Mb3, 0, 1024, nullptr, YTs(0), 1024, 1025, 128, 1024, nullptr, nullptr, Yfr(8), nullptr, YTs(8), 1024, nullptr, c); c += bt.d[1].nblks;
    bt.d[2] = mk(Gb, 0, 1024, nullptr, Mb3T, 1024, 8, 1024, 1024, nullptr, brow8, nullptr, Gb + 8192, nullptr, 0, nullptr, c); c += bt.d[2].nblks;
    bt.nd = 3;
    gemmz<<<dim3(c), dim3(256), 0, stream>>>(bt);
  }
  // L5: M32 ; [g2,g3] = [g0,g1]*W16 + b16
  {
    GBatch bt{}; int c = 0;
    bt.d[0] = mk(Mb1, 0, 1024, nullptr, Mb1T, 1024, 1025, 1024, 1024, brow16, nullptr, nullptr, Mb2, Mb2T, 1024, brow32, c); c += bt.d[0].nblks;
    bt.d[1] = mk(Gb, 0, 1024, nullptr, Mb1T, 1024, 16, 1024, 1024, nullptr, brow16, nullptr, Gb + 16384, nullptr, 0, nullptr, c); c += bt.d[1].nblks;
    bt.nd = 2;
    gemmz<<<dim3(c), dim3(256), 0, stream>>>(bt);
  }
  // L6: [g4..g7] = [g0..g3]*W32 + b32
  {
    GBatch bt{}; int c = 0;
    bt.d[0] = mk(Gb, 0, 1024, nullptr, Mb2T, 1024, 32, 1024, 1024, nullptr, brow32, nullptr, Gb + 32768, nullptr, 0, nullptr, c); c += bt.d[0].nblks;
    bt.nd = 1;
    gemmz<<<dim3(c), dim3(256), 0, stream>>>(bt);
  }
  // L7: qH_r = G*Y_r-top + Y_r-bias (r=1..8) ; qF = emb[rowmap]*Wc + qb
  {
    GBatch bt{}; int c = 0;
    for (int r = 1; r <= 8; ++r) {
      bt.d[r - 1] = mk(Gb, 0, 1024, nullptr, YTs(r), 1024, 64, 128, 1024, nullptr,
                       Yfr(r) + 131072, qH + (long)(r - 1) * 8192, nullptr, nullptr,
                       0, nullptr, c);
      c += bt.d[r - 1].nblks;
    }
    bt.d[8] = mk(emb, 1, 768, rowmap, WcT, 768, 512, 128, 768, nullptr, qb, qF,
                 nullptr, nullptr, 0, nullptr, c);
    c += bt.d[8].nblks;
    bt.nd = 9;
    gemmz<<<dim3(c), dim3(256), 0, stream>>>(bt);
  }
  katt<<<dim3(256), dim3(256), 0, stream>>>(qF, qH, ctxp, V, out);
}

// Round 6
// 151.938 us; speedup vs baseline: 3.7337x; 1.0479x over previous
//
#include <hip/hip_runtime.h>
#include <hip/hip_bf16.h>

#define EMB 768
#define HD 1024
#define D3 128
#define CTXN 512
#define BB 8
#define SS 64

typedef __attribute__((ext_vector_type(8))) short short8v;
typedef __attribute__((ext_vector_type(4))) float f32x4;

__device__ __forceinline__ float fast_tanh(float x) {
  float e = __expf(2.f * x);
  return 1.f - 2.f * __builtin_amdgcn_rcpf(e + 1.f);
}
__device__ __forceinline__ float bf2f(__hip_bfloat16 x) { return __bfloat162float(x); }

struct GDesc {
  const void* A;                 // row-major [M][K], fp32 or bf16
  const __hip_bfloat16* BT;      // transposed B: [N][K] bf16
  const int* arowmap;            // optional A row gather
  const float* addrow_f;         // added to row M-1 only (affine-aug compose)
  const float* bias_f;           // added to all rows
  float* Cf;                     // fp32 row-major out
  __hip_bfloat16* Cb;            // bf16 row-major out
  __hip_bfloat16* CbT;           // bf16 transposed out [N][ldct], rows<1024 only
  float* brow_f;                 // fp32 copy of row M-1
  int M, N, K, lda, ldbt, ldct, af32, mtiles, blk0, nblks;
};
struct GBatch { GDesc d[10]; int nd; };

// gemmz: 32x64 tile, BK=128, 4 waves (each 16x32), XOR-swizzled LDS, dbuf.
// 8 MFMA per wave between barriers (was 4 at BK=64) -> half the vmcnt drains.
__global__ __launch_bounds__(256) void gemmz(GBatch bat) {
  int bx = blockIdx.x;
  GDesc d = bat.d[0];
  for (int i = 1; i < bat.nd; ++i)
    if (bx >= bat.d[i].blk0) d = bat.d[i];
  int local = bx - d.blk0;
  int mt = local % d.mtiles, nt = local / d.mtiles;
  int bm0 = mt * 32, bn0 = nt * 64;

  __shared__ __hip_bfloat16 As[2][32][128];  // swizzled: 16B-chunk ^ (row&7)
  __shared__ __hip_bfloat16 Bs[2][64][128];
  int tid = threadIdx.x, lane = tid & 63, wid = tid >> 6;
  int l16 = lane & 15, g = lane >> 4;
  int wm = (wid & 1) * 16, wn = (wid >> 1) * 32;
  int arow = tid >> 3, aseg = tid & 7;  // A: 32 rows, 16 el/thread (chunks 2a,2a+1)
  int brow = tid >> 2, bseg = tid & 3;  // B: 64 rows, 32 el/thread (chunks 4b..4b+3)
  f32x4 acc[2] = {};

  int agr = bm0 + arow;
  int asrc = (agr < d.M) ? (d.arowmap ? d.arowmap[agr] : agr) : -1;
  const float* Af = (const float*)d.A;
  const __hip_bfloat16* Ab = (const __hip_bfloat16*)d.A;

  float fa[16];
  short8v ba0 = {}, ba1 = {}, bb0 = {}, bb1 = {}, bb2 = {}, bb3 = {};
  int nk = d.K >> 7;

  auto LD = [&](int k0) {
    if (d.af32) {
      if (asrc >= 0) {
        const float* s = Af + (long)asrc * d.lda + k0 + aseg * 16;
#pragma unroll
        for (int j = 0; j < 16; ++j) fa[j] = s[j];
      } else {
#pragma unroll
        for (int j = 0; j < 16; ++j) fa[j] = 0.f;
      }
    } else {
      if (asrc >= 0) {
        const __hip_bfloat16* s = Ab + (long)asrc * d.lda + k0 + aseg * 16;
        ba0 = *(const short8v*)s;
        ba1 = *(const short8v*)(s + 8);
      } else {
        short8v z = {};
        ba0 = z; ba1 = z;
      }
    }
    const __hip_bfloat16* bsrc = d.BT + (long)(bn0 + brow) * d.ldbt + k0 + bseg * 32;
    bb0 = *(const short8v*)bsrc;
    bb1 = *(const short8v*)(bsrc + 8);
    bb2 = *(const short8v*)(bsrc + 16);
    bb3 = *(const short8v*)(bsrc + 24);
  };
  auto ST = [&](int buf) {
    int rs = arow & 7;
    if (d.af32) {
      __hip_bfloat16 t8[16];
#pragma unroll
      for (int j = 0; j < 16; ++j) t8[j] = __float2bfloat16(fa[j]);
      *(short8v*)&As[buf][arow][((2 * aseg) ^ rs) * 8] = *(short8v*)t8;
      *(short8v*)&As[buf][arow][((2 * aseg + 1) ^ rs) * 8] = *(short8v*)(t8 + 8);
    } else {
      *(short8v*)&As[buf][arow][((2 * aseg) ^ rs) * 8] = ba0;
      *(short8v*)&As[buf][arow][((2 * aseg + 1) ^ rs) * 8] = ba1;
    }
    int rb = brow & 7;
    *(short8v*)&Bs[buf][brow][((4 * bseg) ^ rb) * 8] = bb0;
    *(short8v*)&Bs[buf][brow][((4 * bseg + 1) ^ rb) * 8] = bb1;
    *(short8v*)&Bs[buf][brow][((4 * bseg + 2) ^ rb) * 8] = bb2;
    *(short8v*)&Bs[buf][brow][((4 * bseg + 3) ^ rb) * 8] = bb3;
  };

  LD(0);
  ST(0);
  __syncthreads();
  for (int it = 0; it < nk; ++it) {
    int cur = it & 1;
    if (it + 1 < nk) LD((it + 1) << 7);
    int ar = wm + l16;
    int ars = ar & 7;
#pragma unroll
    for (int kf = 0; kf < 4; ++kf) {
      short8v a = *(const short8v*)&As[cur][ar][((kf * 4 + g) ^ ars) * 8];
#pragma unroll
      for (int j = 0; j < 2; ++j) {
        int br = wn + j * 16 + l16;
        short8v b = *(const short8v*)&Bs[cur][br][((kf * 4 + g) ^ (br & 7)) * 8];
        acc[j] = __builtin_amdgcn_mfma_f32_16x16x32_bf16(a, b, acc[j], 0, 0, 0);
      }
    }
    if (it + 1 < nk) ST(cur ^ 1);
    __syncthreads();
  }

  // epilogue (final loop sync passed: LDS free)
  float* Cs = (float*)&Bs[0][0][0];  // [64][33] floats = 8448 B
  bool doT = (d.CbT != nullptr);
#pragma unroll
  for (int j = 0; j < 2; ++j)
#pragma unroll
    for (int r = 0; r < 4; ++r) {
      int gl = wm + g * 4 + r, cl = wn + j * 16 + l16;
      int grow = bm0 + gl, gcol = bn0 + cl;
      float v = acc[j][r];
      if (d.bias_f) v += d.bias_f[gcol];
      if (d.addrow_f && grow == d.M - 1) v += d.addrow_f[gcol];
      if (grow < d.M) {
        if (d.Cf) d.Cf[(long)grow * d.N + gcol] = v;
        if (d.Cb) d.Cb[(long)grow * d.N + gcol] = __float2bfloat16(v);
        if (d.brow_f && grow == d.M - 1) d.brow_f[gcol] = v;
      }
      if (doT) Cs[cl * 33 + gl] = v;
    }
  if (doT) {
    __syncthreads();
    int ctrows = d.M < 1024 ? d.M : 1024;
    int n = tid >> 2, ms = (tid & 3) * 8;
    int gm0 = bm0 + ms;
    __hip_bfloat16 t8[8];
#pragma unroll
    for (int jj = 0; jj < 8; ++jj) t8[jj] = __float2bfloat16(Cs[n * 33 + ms + jj]);
    if (gm0 + 7 < ctrows) {
      *(short8v*)&d.CbT[(long)(bn0 + n) * d.ldct + gm0] = *(short8v*)t8;
    } else {
#pragma unroll
      for (int jj = 0; jj < 8; ++jj)
        if (gm0 + jj < ctrows) d.CbT[(long)(bn0 + n) * d.ldct + gm0 + jj] = t8[jj];
    }
  }
}

// kcast: Maug1 bf16, transposes (W_s^T, Wa_bot^T, Wah^T, Wa_top^T), g0, qb, rowmap
__global__ __launch_bounds__(256) void kcast(const float* __restrict__ W_s,
                                             const float* __restrict__ b_s,
                                             const float* __restrict__ context,
                                             const float* __restrict__ b_in,
                                             const float* __restrict__ W_att_in,
                                             const float* __restrict__ b_att_in,
                                             const float* __restrict__ W_att_h,
                                             const int* __restrict__ ids,
                                             __hip_bfloat16* __restrict__ Mb0,
                                             __hip_bfloat16* __restrict__ Mb0T,
                                             __hip_bfloat16* __restrict__ Y0T,
                                             __hip_bfloat16* __restrict__ WahT,
                                             __hip_bfloat16* __restrict__ WaiT,
                                             __hip_bfloat16* __restrict__ Gb,
                                             float* __restrict__ qb,
                                             int* __restrict__ rowmap) {
  int blk = blockIdx.x, tid = threadIdx.x;
  __shared__ __hip_bfloat16 tl[64][65];
  __shared__ float red[2][128];

  auto TP = [&](const float* src, int R, int C, __hip_bfloat16* dst, int tr, int tc) {
    int r0 = tr * 64, c0 = tc * 64;
    {
      int r = tid >> 2, cs = (tid & 3) * 16;
      const float* s = src + (long)(r0 + r) * C + c0 + cs;
#pragma unroll
      for (int j = 0; j < 16; ++j) tl[cs + j][r] = __float2bfloat16(s[j]);
    }
    __syncthreads();
    {
      int c = tid >> 2, rs = (tid & 3) * 16;
      __hip_bfloat16 o[16];
#pragma unroll
      for (int j = 0; j < 16; ++j) o[j] = tl[c][rs + j];
      *(short8v*)&dst[(long)(c0 + c) * R + r0 + rs] = *(short8v*)&o[0];
      *(short8v*)&dst[(long)(c0 + c) * R + r0 + rs + 8] = *(short8v*)&o[8];
    }
  };

  if (blk < 256) {
    long base = (long)blk * 4096;
    for (int i = tid; i < 4096; i += 256)
      Mb0[base + i] = __float2bfloat16(W_s[base + i]);
  } else if (blk == 256) {
    for (int i = tid; i < HD; i += 256)
      Mb0[(long)HD * HD + i] = __float2bfloat16(b_s[i]);
  } else if (blk < 513) {
    int t = blk - 257;
    TP(W_s, 1024, 1024, Mb0T, t >> 4, t & 15);
  } else if (blk < 545) {
    int t = blk - 513;
    TP(W_att_in + (long)1024 * D3, 1024, 128, Y0T, t >> 1, t & 1);
  } else if (blk < 577) {
    int t = blk - 545;
    TP(W_att_h, 1024, 128, WahT, t >> 1, t & 1);
  } else if (blk < 609) {
    int t = blk - 577;
    TP(W_att_in, 1024, 128, WaiT, t >> 1, t & 1);
  } else if (blk == 609) {
    for (int i = tid; i < BB * HD; i += 256) {
      int b = i >> 10, k = i & 1023;
      Gb[i] = __float2bfloat16(context[((long)b * CTXN + CTXN - 1) * HD + k]);
    }
  } else if (blk == 610) {
    int dd = tid & 127, h = tid >> 7;
    float acc = 0.f;
    for (int k = h * 512; k < h * 512 + 512; ++k)
      acc += b_in[k] * W_att_in[k * D3 + dd];
    red[h][dd] = acc;
    __syncthreads();
    if (h == 0) qb[dd] = red[0][dd] + red[1][dd] + b_att_in[dd];
  } else {
    for (int i = tid; i < 512; i += 256) {
      int t = i >> 3, b = i & 7;
      rowmap[i] = ids[b * SS + t];
    }
  }
}

// katt: out[b][t][c] = sum_d V[d]*tanh(qF[t*8+b][d] + qH[t&7][(t>>3)*8+b][d] + ctxp[b][c][d])
__global__ __launch_bounds__(256) void katt(const float* __restrict__ qF,
                                            const float* __restrict__ qH,
                                            const float* __restrict__ ctxp,
                                            const float* __restrict__ V,
                                            float* __restrict__ out) {
  int blk = blockIdx.x;
  int b = blk >> 5, tt = (blk >> 4) & 1, ct = blk & 15;
  int t0 = tt * 32, c0 = ct * 32;
  int tid = threadIdx.x;
  __shared__ float lq[32][128];
  __shared__ float lc[32][132];
  __shared__ float lv[128];
  for (int i = tid; i < 32 * 128; i += 256) {
    int r = i >> 7, d = i & 127;
    int t = t0 + r;
    lq[r][d] = qF[((long)t * 8 + b) * 128 + d] +
               qH[(((long)(t & 7)) * 64 + (t >> 3) * 8 + b) * 128 + d];
    lc[r][d] = ctxp[((long)b * CTXN + c0 + r) * D3 + d];
  }
  if (tid < 128) lv[tid] = V[tid];
  __syncthreads();
  int cl = tid & 31, tg = tid >> 5;
  float r[4] = {0.f, 0.f, 0.f, 0.f};
  for (int d4 = 0; d4 < 32; ++d4) {
    float4 cv = *reinterpret_cast<const float4*>(&lc[cl][d4 * 4]);
    float4 vv = *reinterpret_cast<const float4*>(&lv[d4 * 4]);
#pragma unroll
    for (int u = 0; u < 4; ++u) {
      int t = tg + u * 8;
      float4 qv = *reinterpret_cast<const float4*>(&lq[t][d4 * 4]);
      r[u] = fmaf(vv.x, fast_tanh(qv.x + cv.x), r[u]);
      r[u] = fmaf(vv.y, fast_tanh(qv.y + cv.y), r[u]);
      r[u] = fmaf(vv.z, fast_tanh(qv.z + cv.z), r[u]);
      r[u] = fmaf(vv.w, fast_tanh(qv.w + cv.w), r[u]);
    }
  }
#pragma unroll
  for (int u = 0; u < 4; ++u) {
    int t = tg + u * 8;
    out[((long)b * SS + (t0 + t)) * CTXN + c0 + cl] = r[u];
  }
  if (blk == 0) {
    for (int i = tid; i < SS * BB; i += 256) out[(long)BB * SS * CTXN + i] = 0.f;
  }
}

static inline GDesc mk(const void* A, int af32, int lda, const int* arowmap,
                       const __hip_bfloat16* BT, int ldbt, int M, int N, int K,
                       const float* addrow_f, const float* bias_f, float* Cf,
                       __hip_bfloat16* Cb, __hip_bfloat16* CbT, int ldct,
                       float* brow_f, int blk0) {
  GDesc d;
  d.A = A; d.BT = BT; d.arowmap = arowmap;
  d.addrow_f = addrow_f; d.bias_f = bias_f;
  d.Cf = Cf; d.Cb = Cb; d.CbT = CbT; d.brow_f = brow_f;
  d.M = M; d.N = N; d.K = K; d.lda = lda; d.ldbt = ldbt; d.ldct = ldct;
  d.af32 = af32;
  d.mtiles = (M + 31) >> 5;
  d.blk0 = blk0;
  d.nblks = d.mtiles * (N >> 6);
  return d;
}

extern "C" void kernel_launch(void* const* d_in, const int* in_sizes, int n_in,
                              void* d_out, int out_size, void* d_ws, size_t ws_size,
                              hipStream_t stream) {
  const int* ids = (const int*)d_in[0];
  const float* context = (const float*)d_in[4];
  const float* emb = (const float*)d_in[5];
  const float* W_in = (const float*)d_in[6];
  const float* b_in = (const float*)d_in[7];
  const float* W_s = (const float*)d_in[8];
  const float* b_s = (const float*)d_in[9];
  const float* W_att_in = (const float*)d_in[10];
  const float* b_att_in = (const float*)d_in[11];
  const float* W_att_h = (const float*)d_in[12];
  const float* b_att_h = (const float*)d_in[13];
  const float* V = (const float*)d_in[14];

  float* ws = (float*)d_ws;
  float* ctxp = ws;                     // 524288
  float* Yf = ctxp + 524288;            // 9*131200 (slot r, r=0 unused)
  float* qF = Yf + 1180800;             // 65536
  float* qH = qF + 65536;               // 8*64*128 = 65536
  float* qb = qH + 65536;               // 128
  float* brow2 = qb + 128;              // 1024 each
  float* brow4 = brow2 + 1024;
  float* brow8 = brow4 + 1024;
  float* brow16 = brow8 + 1024;
  float* brow32 = brow16 + 1024;
  int* rowmap = (int*)(brow32 + 1024);  // 512
  __hip_bfloat16* bfp = (__hip_bfloat16*)(rowmap + 512);
  __hip_bfloat16* Mb0 = bfp;            // 1025*1024
  __hip_bfloat16* Mb0T = Mb0 + 1049600; // 1024*1024
  __hip_bfloat16* Mb1 = Mb0T + 1048576;
  __hip_bfloat16* Mb1T = Mb1 + 1049600;
  __hip_bfloat16* Mb2 = Mb1T + 1048576;
  __hip_bfloat16* Mb2T = Mb2 + 1049600;
  __hip_bfloat16* Mb3 = Mb2T + 1048576;
  __hip_bfloat16* Mb3T = Mb3 + 1049600;
  __hip_bfloat16* YT = Mb3T + 1048576;  // 9 slots * 131072
  __hip_bfloat16* WahT = YT + 9 * 131072;
  __hip_bfloat16* WaiT = WahT + 131072;
  __hip_bfloat16* WcT = WaiT + 131072;  // [128][768]
  __hip_bfloat16* Gb = WcT + 131072;    // 64*1024
  float* out = (float*)d_out;

  auto Yfr = [&](int r) { return Yf + (long)r * 131200; };
  auto YTs = [&](int r) { return YT + (long)r * 131072; };

  kcast<<<dim3(612), dim3(256), 0, stream>>>(W_s, b_s, context, b_in, W_att_in,
                                             b_att_in, W_att_h, ids, Mb0, Mb0T,
                                             YTs(0), WahT, WaiT, Gb, qb, rowmap);
  // L1: M2 = M1^2 ; Y1 = M1*Y0 ; ctx_proj ; Wc
  {
    GBatch bt{}; int c = 0;
    bt.d[0] = mk(Mb0, 0, 1024, nullptr, Mb0T, 1024, 1025, 1024, 1024, b_s, nullptr, nullptr, Mb1, Mb1T, 1024, brow2, c); c += bt.d[0].nblks;
    bt.d[1] = mk(Mb0, 0, 1024, nullptr, YTs(0), 1024, 1025, 128, 1024, nullptr, nullptr, Yfr(1), nullptr, YTs(1), 1024, nullptr, c); c += bt.d[1].nblks;
    bt.d[2] = mk(context, 1, 1024, nullptr, WahT, 1024, 4096, 128, 1024, nullptr, b_att_h, ctxp, nullptr, nullptr, 0, nullptr, c); c += bt.d[2].nblks;
    bt.d[3] = mk(W_in, 1, 1024, nullptr, WaiT, 1024, 768, 128, 1024, nullptr, nullptr, nullptr, nullptr, WcT, 768, nullptr, c); c += bt.d[3].nblks;
    bt.nd = 4;
    gemmz<<<dim3(c), dim3(256), 0, stream>>>(bt);
  }
  // L2: M4 ; Y2 = M2*Y0 ; Y3 = M2∘Y1
  {
    GBatch bt{}; int c = 0;
    bt.d[0] = mk(Mb1, 0, 1024, nullptr, Mb1T, 1024, 1025, 1024, 1024, brow2, nullptr, nullptr, Mb2, Mb2T, 1024, brow4, c); c += bt.d[0].nblks;
    bt.d[1] = mk(Mb1, 0, 1024, nullptr, YTs(0), 1024, 1025, 128, 1024, nullptr, nullptr, Yfr(2), nullptr, YTs(2), 1024, nullptr, c); c += bt.d[1].nblks;
    bt.d[2] = mk(Mb1, 0, 1024, nullptr, YTs(1), 1024, 1025, 128, 1024, Yfr(1) + 131072, nullptr, Yfr(3), nullptr, YTs(3), 1024, nullptr, c); c += bt.d[2].nblks;
    bt.nd = 3;
    gemmz<<<dim3(c), dim3(256), 0, stream>>>(bt);
  }
  // L3: M8 ; Y4..Y7 = M4∘Y0..Y3
  {
    GBatch bt{}; int c = 0;
    bt.d[0] = mk(Mb2, 0, 1024, nullptr, Mb2T, 1024, 1025, 1024, 1024, brow4, nullptr, nullptr, Mb3, Mb3T, 1024, brow8, c); c += bt.d[0].nblks;
    for (int s = 0; s < 4; ++s) {
      bt.d[1 + s] = mk(Mb2, 0, 1024, nullptr, YTs(s), 1024, 1025, 128, 1024,
                       (s == 0) ? nullptr : (Yfr(s) + 131072), nullptr,
                       Yfr(4 + s), nullptr, YTs(4 + s), 1024, nullptr, c);
      c += bt.d[1 + s].nblks;
    }
    bt.nd = 5;
    gemmz<<<dim3(c), dim3(256), 0, stream>>>(bt);
  }
  // L4: M16 ; Y8 = M8*Y0 ; g1 = g0*W8 + b8
  {
    GBatch bt{}; int c = 0;
    bt.d[0] = mk(Mb3, 0, 1024, nullptr, Mb3T, 1024, 1025, 1024, 1024, brow8, nullptr, nullptr, Mb1, Mb1T, 1024, brow16, c); c += bt.d[0].nblks;
    bt.d[1] = mk(Mb3, 0, 1024, nullptr, YTs(0), 1024, 1025, 128, 1024, nullptr, nullptr, Yfr(8), nullptr, YTs(8), 1024, nullptr, c); c += bt.d[1].nblks;
    bt.d[2] = mk(Gb, 0, 1024, nullptr, Mb3T, 1024, 8, 1024, 1024, nullptr, brow8, nullptr, Gb + 8192, nullptr, 0, nullptr, c); c += bt.d[2].nblks;
    bt.nd = 3;
    gemmz<<<dim3(c), dim3(256), 0, stream>>>(bt);
  }
  // L5: M32 ; [g2,g3] = [g0,g1]*W16 + b16
  {
    GBatch bt{}; int c = 0;
    bt.d[0] = mk(Mb1, 0, 1024, nullptr, Mb1T, 1024, 1025, 1024, 1024, brow16, nullptr, nullptr, Mb2, Mb2T, 1024, brow32, c); c += bt.d[0].nblks;
    bt.d[1] = mk(Gb, 0, 1024, nullptr, Mb1T, 1024, 16, 1024, 1024, nullptr, brow16, nullptr, Gb + 16384, nullptr, 0, nullptr, c); c += bt.d[1].nblks;
    bt.nd = 2;
    gemmz<<<dim3(c), dim3(256), 0, stream>>>(bt);
  }
  // L6: [g4..g7] = [g0..g3]*W32 + b32
  {
    GBatch bt{}; int c = 0;
    bt.d[0] = mk(Gb, 0, 1024, nullptr, Mb2T, 1024, 32, 1024, 1024, nullptr, brow32, nullptr, Gb + 32768, nullptr, 0, nullptr, c); c += bt.d[0].nblks;
    bt.nd = 1;
    gemmz<<<dim3(c), dim3(256), 0, stream>>>(bt);
  }
  // L7: qH_r = G*Y_r-top + Y_r-bias (r=1..8) ; qF = emb[rowmap]*Wc + qb
  {
    GBatch bt{}; int c = 0;
    for (int r = 1; r <= 8; ++r) {
      bt.d[r - 1] = mk(Gb, 0, 1024, nullptr, YTs(r), 1024, 64, 128, 1024, nullptr,
                       Yfr(r) + 131072, qH + (long)(r - 1) * 8192, nullptr, nullptr,
                       0, nullptr, c);
      c += bt.d[r - 1].nblks;
    }
    bt.d[8] = mk(emb, 1, 768, rowmap, WcT, 768, 512, 128, 768, nullptr, qb, qF,
                 nullptr, nullptr, 0, nullptr, c);
    c += bt.d[8].nblks;
    bt.nd = 9;
    gemmz<<<dim3(c), dim3(256), 0, stream>>>(bt);
  }
  katt<<<dim3(256), dim3(256), 0, stream>>>(qF, qH, ctxp, V, out);
}